// Round 6
// baseline (203.381 us; speedup 1.0000x reference)
//
#include <hip/hip_runtime.h>
#include <cstdint>
#include <cstddef>

#define S_DIM 1024
#define NPTS (S_DIM * S_DIM)
#define NLEV 16
#define TBL (1u << 19)
#define TMASK (TBL - 1u)
#define PRIME_Y 2654435761u

typedef float v4f __attribute__((ext_vector_type(4)));
typedef short v8s __attribute__((ext_vector_type(8)));

// ---- split-bf16 helpers: x = hi + lo, both truncated bf16 ----
// pack two fp32 (a=even k, b=odd k) into one dword of 2 bf16 (a in low short).
__device__ __forceinline__ void split2(float a, float b, uint32_t& hi, uint32_t& lo) {
    uint32_t ua = __float_as_uint(a), ub = __float_as_uint(b);
    uint32_t ha = ua & 0xFFFF0000u, hb = ub & 0xFFFF0000u;
    float la = a - __uint_as_float(ha);
    float lb = b - __uint_as_float(hb);
    hi = (ha >> 16) | hb;
    lo = (__float_as_uint(la) >> 16) | (__float_as_uint(lb) & 0xFFFF0000u);
}

// ============================================================================
// Pre-pass: build bf16 hi/lo A-fragments of W0^T (64x32) and W1^T (64x64) in
// d_ws, fragment-linear so the main kernel loads each lane's 16B with one
// coalesced uint4 load.  A-frag (16x16x32): lane holds A[m=lane&15][k=q*8+j].
// ws as uint4: [0,256) W0hi | [256,512) W0lo | [512,1024) W1hi | [1024,1536) W1lo
// ============================================================================
__global__ __launch_bounds__(256) void prep_weights(const float* __restrict__ W0,
                                                    const float* __restrict__ W1,
                                                    uint4* __restrict__ ws) {
    const int tid = threadIdx.x;          // 0..255
    const int lane = tid & 63;
    const int m = lane & 15, q = lane >> 4;

    {   // W0^T: 4 n-tiles, 1 k-step. unit = tile*64+lane = tid.
        const int tile = tid >> 6;
        const int n = tile * 16 + m;
        uint32_t hi[4], lo[4];
        #pragma unroll
        for (int d = 0; d < 4; ++d) {
            const int k0 = q * 8 + 2 * d;
            split2(W0[k0 * 64 + n], W0[(k0 + 1) * 64 + n], hi[d], lo[d]);
        }
        ws[tid]       = make_uint4(hi[0], hi[1], hi[2], hi[3]);
        ws[256 + tid] = make_uint4(lo[0], lo[1], lo[2], lo[3]);
    }

    #pragma unroll
    for (int rep = 0; rep < 2; ++rep) {   // W1^T: 8 frags (nt*2+ks) x 64 lanes
        const int unit = tid + rep * 256;     // 0..511
        const int l2 = unit & 63, frag = unit >> 6;
        const int nt = frag >> 1, ks = frag & 1;
        const int mm = l2 & 15, qq = l2 >> 4;
        const int n = nt * 16 + mm;
        uint32_t hi[4], lo[4];
        #pragma unroll
        for (int d = 0; d < 4; ++d) {
            const int k0 = ks * 32 + qq * 8 + 2 * d;
            split2(W1[k0 * 64 + n], W1[(k0 + 1) * 64 + n], hi[d], lo[d]);
        }
        ws[512 + unit]  = make_uint4(hi[0], hi[1], hi[2], hi[3]);
        ws[1024 + unit] = make_uint4(lo[0], lo[1], lo[2], lo[3]);
    }
}

// ---- per-level hash-grid feature (unchanged, verified all rounds) ----
static __device__ __forceinline__ float2 level_feat(float x, float y, int res,
                                                    const float* __restrict__ tb) {
    const float fr = (float)res;
    const float px = x * fr, py = y * fr;
    const float fx = floorf(px), fy = floorf(py);
    const float wx = px - fx, wy = py - fy;
    const int x0 = (int)fx, y0 = (int)fy;

    int i00, i01, i10, i11;
    const bool dense = ((long long)(res + 1) * (long long)(res + 1) <= (long long)TBL);
    if (dense) {
        const int st = res + 1;
        i00 = x0 + y0 * st;
        i01 = i00 + st;
        i10 = i00 + 1;
        i11 = i01 + 1;
    } else {
        const unsigned a = (unsigned)x0, b = (unsigned)y0;
        const unsigned hb0 = b * PRIME_Y;
        const unsigned hb1 = (b + 1u) * PRIME_Y;
        i00 = (int)((a ^ hb0) & TMASK);
        i01 = (int)((a ^ hb1) & TMASK);
        i10 = (int)(((a + 1u) ^ hb0) & TMASK);
        i11 = (int)(((a + 1u) ^ hb1) & TMASK);
    }

    const float2 f00 = *(const float2*)(tb + 2 * (size_t)i00);
    const float2 f01 = *(const float2*)(tb + 2 * (size_t)i01);
    const float2 f10 = *(const float2*)(tb + 2 * (size_t)i10);
    const float2 f11 = *(const float2*)(tb + 2 * (size_t)i11);

    const float omx = 1.f - wx, omy = 1.f - wy;
    const float w00 = omx * omy, w01 = omx * wy, w10 = wx * omy, w11 = wx * wy;

    float2 e;
    e.x = f00.x * w00 + f01.x * w01 + f10.x * w10 + f11.x * w11;
    e.y = f00.y * w00 + f01.y * w01 + f10.y * w10 + f11.y * w11;
    return e;
}

// ============================================================================
// Main kernel. Round-5 structure (per-point encode, W0/W1 frags in regs,
// h0 HALF-bounce, LDS 46848 -> 3 blocks/CU) with the encode-phase register
// peak cut so the (256,3) ~170-reg budget fits WITHOUT spill:
//   Round-5 lesson: phase 2 needs ~165 regs (W0 32 + W1 64 + acc 32 + frags
//   16 + misc); the allocator's arch/acc split granted only ~84 arch regs,
//   but the old encode (enc[32] floats THEN hi/lo[16] conversion) peaked at
//   ~92 arch -> ~16 dwords/point spilled (79 MB scratch writes).
//   Fix: split-as-you-go encode in GROUPS OF 4 LEVELS — each group computes
//   4 level_feats, split2s them immediately, and retires 2x b128 to encLDS.
//   Live state per group: 16 in-flight gathers + hi[4]/lo[4] ~ 60-70 regs.
//   The unrolled group loop still lets the scheduler overlap the next
//   group's gathers up to the pressure cap (back-off instead of spill).
// Spill tripwire: WRITE_SIZE > 30 MB means the reg budget failed again.
// LDS: enc 36864 + h0half 9216 + w2t 768 = 46848 -> 3 blocks/CU, 12 waves.
// ============================================================================
__global__ __launch_bounds__(256, 3) void ngp_mfma(
    const float* __restrict__ xy,
    const float* __restrict__ tables,
    const float* __restrict__ W2,
    const uint4* __restrict__ ws,
    float* __restrict__ out)
{
    // enc rows: 256 points x (16 hi | 16 lo dwords) = 128B, padded to 144B
    __shared__ alignas(16) uint32_t encLDS[256 * 36];        // 36864 B
    // h0 HALF rows: per wave 16 points x (16 hi | 16 lo dwords) + 4 pad
    __shared__ alignas(16) uint32_t h0LDS[4 * 16 * 36];      //  9216 B
    // W2 transposed: w2t[c][n], c<3, n<64 -> 16B-aligned 4-float reads
    __shared__ alignas(16) float w2t[3 * 64];                //   768 B

    const int tid = threadIdx.x;
    const int lane = tid & 63;
    const int wave = tid >> 6;
    const int m = lane & 15, q = lane >> 4;
    const int blockBase = blockIdx.x * 256;

    if (tid < 192) w2t[(tid % 3) * 64 + (tid / 3)] = W2[tid];

    // ---------------- Phase 1: encode own point (split-as-you-go) ----------
    {
        const int pid = blockBase + tid;
        const float2 p = ((const float2*)xy)[pid];
        constexpr int RES[NLEV] = {16, 24, 36, 54, 81, 121, 182, 273,
                                   410, 615, 922, 1383, 2075, 3113, 4670, 7006};
        uint32_t* row = encLDS + tid * 36;
        #pragma unroll
        for (int g = 0; g < 4; ++g) {
            uint32_t hi[4], lo[4];
            #pragma unroll
            for (int i = 0; i < 4; ++i) {
                const int l = g * 4 + i;
                const float2 e = level_feat(p.x, p.y, RES[l],
                                            tables + (size_t)l * (size_t)(TBL * 2u));
                split2(e.x, e.y, hi[i], lo[i]);
            }
            *((uint4*)(row + 4 * g))      = make_uint4(hi[0], hi[1], hi[2], hi[3]);
            *((uint4*)(row + 16 + 4 * g)) = make_uint4(lo[0], lo[1], lo[2], lo[3]);
        }
    }

    __syncthreads();   // w2t visibility (enc/h0 rows are wave-local)

    // keep encode and weight-frag live ranges disjoint: no motion across here
    __builtin_amdgcn_sched_barrier(0);

    // ---------------- weight fragments: one load per wave, reused 64 pts ----
    v8s w0h[4], w0l[4], w1h[8], w1l[8];
    #pragma unroll
    for (int t = 0; t < 4; ++t) {
        w0h[t] = __builtin_bit_cast(v8s, ws[t * 64 + lane]);
        w0l[t] = __builtin_bit_cast(v8s, ws[256 + t * 64 + lane]);
    }
    #pragma unroll
    for (int f = 0; f < 8; ++f) {
        w1h[f] = __builtin_bit_cast(v8s, ws[512 + f * 64 + lane]);
        w1l[f] = __builtin_bit_cast(v8s, ws[1024 + f * 64 + lane]);
    }

    uint32_t* hrow = h0LDS + (wave * 16 + m) * 36;

    // ---------------- Phase 2: 4 M-tiles of 16 points ----------------
    #pragma unroll 1
    for (int t = 0; t < 4; ++t) {
        // B-frag of enc for this tile: point p = wave*64 + t*16 + m
        const uint32_t* erow = encLDS + (wave * 64 + t * 16 + m) * 36;
        const v8s eH = __builtin_bit_cast(v8s, *((const uint4*)(erow + q * 4)));
        const v8s eL = __builtin_bit_cast(v8s, *((const uint4*)(erow + 16 + q * 4)));

        // ---- L0: D0[n][p] = W0^T x enc^T, 3-term split ----
        v4f acc0[4];
        #pragma unroll
        for (int nt = 0; nt < 4; ++nt) {
            v4f c = {0.f, 0.f, 0.f, 0.f};
            c = __builtin_amdgcn_mfma_f32_16x16x32_bf16(w0l[nt], eH, c, 0, 0, 0);
            c = __builtin_amdgcn_mfma_f32_16x16x32_bf16(w0h[nt], eL, c, 0, 0, 0);
            c = __builtin_amdgcn_mfma_f32_16x16x32_bf16(w0h[nt], eH, c, 0, 0, 0);
            acc0[nt] = c;
        }

        v4f acc1[4];
        #pragma unroll
        for (int nt = 0; nt < 4; ++nt) acc1[nt] = (v4f){0.f, 0.f, 0.f, 0.f};

        // ---- L1 in two ks-halves through the half-size bounce buffer ----
        // half ks: relu+split acc0[2ks],acc0[2ks+1] (n in [32ks, 32ks+32)) ->
        // bounce -> B-frags (k = 32ks + q*8 + j for point m) -> 12 MFMAs.
        #pragma unroll
        for (int ks = 0; ks < 2; ++ks) {
            #pragma unroll
            for (int nh = 0; nh < 2; ++nh) {
                const int nt = ks * 2 + nh;
                const float r0 = fmaxf(acc0[nt][0], 0.f), r1 = fmaxf(acc0[nt][1], 0.f);
                const float r2 = fmaxf(acc0[nt][2], 0.f), r3 = fmaxf(acc0[nt][3], 0.f);
                uint32_t h0w, l0w, h1w, l1w;
                split2(r0, r1, h0w, l0w);
                split2(r2, r3, h1w, l1w);
                *((uint2*)(hrow + nh * 8 + q * 2))      = make_uint2(h0w, h1w);
                *((uint2*)(hrow + 16 + nh * 8 + q * 2)) = make_uint2(l0w, l1w);
            }
            const v8s bH = __builtin_bit_cast(v8s, *((const uint4*)(hrow + q * 4)));
            const v8s bL = __builtin_bit_cast(v8s, *((const uint4*)(hrow + 16 + q * 4)));

            #pragma unroll
            for (int nt = 0; nt < 4; ++nt) {
                v4f c = acc1[nt];
                c = __builtin_amdgcn_mfma_f32_16x16x32_bf16(w1l[nt*2+ks], bH, c, 0, 0, 0);
                c = __builtin_amdgcn_mfma_f32_16x16x32_bf16(w1h[nt*2+ks], bL, c, 0, 0, 0);
                c = __builtin_amdgcn_mfma_f32_16x16x32_bf16(w1h[nt*2+ks], bH, c, 0, 0, 0);
                acc1[nt] = c;
            }
        }

        // ---- L2 (64->3) in VALU: lane sums its 16 n's, quad-reduce ----
        float o0 = 0.f, o1 = 0.f, o2 = 0.f;
        #pragma unroll
        for (int nt = 0; nt < 4; ++nt) {
            const int n = nt * 16 + q * 4;
            const float4 wa = *((const float4*)(w2t + 0 * 64 + n));
            const float4 wb = *((const float4*)(w2t + 1 * 64 + n));
            const float4 wc = *((const float4*)(w2t + 2 * 64 + n));
            const float h0r = fmaxf(acc1[nt][0], 0.f), h1r = fmaxf(acc1[nt][1], 0.f);
            const float h2r = fmaxf(acc1[nt][2], 0.f), h3r = fmaxf(acc1[nt][3], 0.f);
            o0 = fmaf(h0r, wa.x, fmaf(h1r, wa.y, fmaf(h2r, wa.z, fmaf(h3r, wa.w, o0))));
            o1 = fmaf(h0r, wb.x, fmaf(h1r, wb.y, fmaf(h2r, wb.z, fmaf(h3r, wb.w, o1))));
            o2 = fmaf(h0r, wc.x, fmaf(h1r, wc.y, fmaf(h2r, wc.z, fmaf(h3r, wc.w, o2))));
        }
        o0 += __shfl_xor(o0, 16); o0 += __shfl_xor(o0, 32);
        o1 += __shfl_xor(o1, 16); o1 += __shfl_xor(o1, 32);
        o2 += __shfl_xor(o2, 16); o2 += __shfl_xor(o2, 32);

        if (lane < 16) {
            const int p = blockBase + wave * 64 + t * 16 + lane;
            out[p] = o0;
            out[NPTS + p] = o1;
            out[2 * NPTS + p] = o2;
        }
    }
}

extern "C" void kernel_launch(void* const* d_in, const int* in_sizes, int n_in,
                              void* d_out, int out_size, void* d_ws, size_t ws_size,
                              hipStream_t stream) {
    const float* xy     = (const float*)d_in[0];
    const float* tables = (const float*)d_in[1];
    const float* W0     = (const float*)d_in[2];
    const float* W1     = (const float*)d_in[3];
    const float* W2     = (const float*)d_in[4];
    float* out = (float*)d_out;
    uint4* ws  = (uint4*)d_ws;   // 1536 x 16B = 24 KB

    hipLaunchKernelGGL(prep_weights, dim3(1), dim3(256), 0, stream, W0, W1, ws);
    hipLaunchKernelGGL(ngp_mfma, dim3(NPTS / 256), dim3(256), 0, stream,
                       xy, tables, W2, ws, out);
}

// Round 7
// 173.108 us; speedup vs baseline: 1.1749x; 1.1749x over previous
//
#include <hip/hip_runtime.h>
#include <cstdint>
#include <cstddef>

#define S_DIM 1024
#define NPTS (S_DIM * S_DIM)
#define NLEV 16
#define TBL (1u << 19)
#define TMASK (TBL - 1u)
#define PRIME_Y 2654435761u

typedef float v4f __attribute__((ext_vector_type(4)));
typedef short v8s __attribute__((ext_vector_type(8)));

// ---- split-bf16 helpers: x = hi + lo, both truncated bf16 ----
// pack two fp32 (a=even k, b=odd k) into one dword of 2 bf16 (a in low short).
__device__ __forceinline__ void split2(float a, float b, uint32_t& hi, uint32_t& lo) {
    uint32_t ua = __float_as_uint(a), ub = __float_as_uint(b);
    uint32_t ha = ua & 0xFFFF0000u, hb = ub & 0xFFFF0000u;
    float la = a - __uint_as_float(ha);
    float lb = b - __uint_as_float(hb);
    hi = (ha >> 16) | hb;
    lo = (__float_as_uint(la) >> 16) | (__float_as_uint(lb) & 0xFFFF0000u);
}

// ============================================================================
// Pre-pass: build bf16 hi/lo A-fragments of W0^T (64x32) and W1^T (64x64) in
// d_ws, fragment-linear so the main kernel loads each lane's 16B with one
// coalesced uint4 load.  A-frag (16x16x32): lane holds A[m=lane&15][k=q*8+j].
// ws as uint4: [0,256) W0hi | [256,512) W0lo | [512,1024) W1hi | [1024,1536) W1lo
// ============================================================================
__global__ __launch_bounds__(256) void prep_weights(const float* __restrict__ W0,
                                                    const float* __restrict__ W1,
                                                    uint4* __restrict__ ws) {
    const int tid = threadIdx.x;          // 0..255
    const int lane = tid & 63;
    const int m = lane & 15, q = lane >> 4;

    {   // W0^T: 4 n-tiles, 1 k-step. unit = tile*64+lane = tid.
        const int tile = tid >> 6;
        const int n = tile * 16 + m;
        uint32_t hi[4], lo[4];
        #pragma unroll
        for (int d = 0; d < 4; ++d) {
            const int k0 = q * 8 + 2 * d;
            split2(W0[k0 * 64 + n], W0[(k0 + 1) * 64 + n], hi[d], lo[d]);
        }
        ws[tid]       = make_uint4(hi[0], hi[1], hi[2], hi[3]);
        ws[256 + tid] = make_uint4(lo[0], lo[1], lo[2], lo[3]);
    }

    #pragma unroll
    for (int rep = 0; rep < 2; ++rep) {   // W1^T: 8 frags (nt*2+ks) x 64 lanes
        const int unit = tid + rep * 256;     // 0..511
        const int l2 = unit & 63, frag = unit >> 6;
        const int nt = frag >> 1, ks = frag & 1;
        const int mm = l2 & 15, qq = l2 >> 4;
        const int n = nt * 16 + mm;
        uint32_t hi[4], lo[4];
        #pragma unroll
        for (int d = 0; d < 4; ++d) {
            const int k0 = ks * 32 + qq * 8 + 2 * d;
            split2(W1[k0 * 64 + n], W1[(k0 + 1) * 64 + n], hi[d], lo[d]);
        }
        ws[512 + unit]  = make_uint4(hi[0], hi[1], hi[2], hi[3]);
        ws[1024 + unit] = make_uint4(lo[0], lo[1], lo[2], lo[3]);
    }
}

// ---- per-level hash-grid feature (unchanged, verified all rounds) ----
static __device__ __forceinline__ float2 level_feat(float x, float y, int res,
                                                    const float* __restrict__ tb) {
    const float fr = (float)res;
    const float px = x * fr, py = y * fr;
    const float fx = floorf(px), fy = floorf(py);
    const float wx = px - fx, wy = py - fy;
    const int x0 = (int)fx, y0 = (int)fy;

    int i00, i01, i10, i11;
    const bool dense = ((long long)(res + 1) * (long long)(res + 1) <= (long long)TBL);
    if (dense) {
        const int st = res + 1;
        i00 = x0 + y0 * st;
        i01 = i00 + st;
        i10 = i00 + 1;
        i11 = i01 + 1;
    } else {
        const unsigned a = (unsigned)x0, b = (unsigned)y0;
        const unsigned hb0 = b * PRIME_Y;
        const unsigned hb1 = (b + 1u) * PRIME_Y;
        i00 = (int)((a ^ hb0) & TMASK);
        i01 = (int)((a ^ hb1) & TMASK);
        i10 = (int)(((a + 1u) ^ hb0) & TMASK);
        i11 = (int)(((a + 1u) ^ hb1) & TMASK);
    }

    const float2 f00 = *(const float2*)(tb + 2 * (size_t)i00);
    const float2 f01 = *(const float2*)(tb + 2 * (size_t)i01);
    const float2 f10 = *(const float2*)(tb + 2 * (size_t)i10);
    const float2 f11 = *(const float2*)(tb + 2 * (size_t)i11);

    const float omx = 1.f - wx, omy = 1.f - wy;
    const float w00 = omx * omy, w01 = omx * wy, w10 = wx * omy, w11 = wx * wy;

    float2 e;
    e.x = f00.x * w00 + f01.x * w01 + f10.x * w10 + f11.x * w11;
    e.y = f00.y * w00 + f01.y * w01 + f10.y * w10 + f11.y * w11;
    return e;
}

// ============================================================================
// Main kernel. Per-point encode (proven spill-free), 3 blocks/CU, NO spill:
//   Rounds 5-6 lesson: phase-2 cold state with W1 in regs = ~212 total demand
//   vs (256,3)'s 168-reg budget -> structural spill (80 MB scratch).  W1 must
//   live in LDS.  Round-4 lesson: LDS occupancy granule is 2048 B; 3 blocks
//   need <= 53248 B after rounding.
// The fit (exactly 53248 = enc 36864 + w1 16384):
//   - h0 bounce buffer ELIMINATED: tile t's bounce reuses tile t's own enc
//     rows (eH/eL already in regs; same-wave DS ops complete in issue order;
//     rows are wave-exclusive; each tile only trashes its own rows).
//   - w2t ELIMINATED: W2 (768 B, L1-resident) read per nt as 3 float4 with
//     register shuffle (r4-verified pattern), tOff-laundered against LICM.
//   - W1 frags in w1LDS (staged once, 4 uint4/thread), per-tile reads with
//     laundered index so 64 dwords don't get hoisted out of the t-loop.
// Register audit at (256,3): cold = W0 32 + acc 32 + ptrs ~10; arch peaks
// (encode ~84, phase-2 transients ~90) -> ~155 <= 168 -> no spill expected.
// Spill tripwire: WRITE_SIZE > 30 MB means the reg budget failed again.
// ============================================================================
__global__ __launch_bounds__(256, 3) void ngp_mfma(
    const float* __restrict__ xy,
    const float* __restrict__ tables,
    const float* __restrict__ W2,
    const uint4* __restrict__ ws,
    float* __restrict__ out)
{
    // enc rows: 256 points x (16 hi | 16 lo dwords) = 128B, padded to 144B.
    // Rows double as the per-tile h0 bounce space (see header comment).
    __shared__ alignas(16) uint32_t encLDS[256 * 36];        // 36864 B
    // W1^T fragments: [0,512) hi, [512,1024) lo, lane-linear 16B units
    __shared__ alignas(16) uint4 w1LDS[1024];                // 16384 B
    // total: 53248 B = 26 x 2048 exactly -> 3 blocks/CU

    const int tid = threadIdx.x;
    const int lane = tid & 63;
    const int wave = tid >> 6;
    const int m = lane & 15, q = lane >> 4;
    const int blockBase = blockIdx.x * 256;

    // stage W1 frags global->LDS (1024 uint4, 4 per thread); visible after
    // the __syncthreads below (encode runs in between, hiding the latency).
    #pragma unroll
    for (int i = 0; i < 4; ++i) w1LDS[tid + 256 * i] = ws[512 + tid + 256 * i];

    // ---------------- Phase 1: encode own point (split-as-you-go) ----------
    {
        const int pid = blockBase + tid;
        const float2 p = ((const float2*)xy)[pid];
        constexpr int RES[NLEV] = {16, 24, 36, 54, 81, 121, 182, 273,
                                   410, 615, 922, 1383, 2075, 3113, 4670, 7006};
        uint32_t* row = encLDS + tid * 36;
        #pragma unroll
        for (int g = 0; g < 4; ++g) {
            uint32_t hi[4], lo[4];
            #pragma unroll
            for (int i = 0; i < 4; ++i) {
                const int l = g * 4 + i;
                const float2 e = level_feat(p.x, p.y, RES[l],
                                            tables + (size_t)l * (size_t)(TBL * 2u));
                split2(e.x, e.y, hi[i], lo[i]);
            }
            *((uint4*)(row + 4 * g))      = make_uint4(hi[0], hi[1], hi[2], hi[3]);
            *((uint4*)(row + 16 + 4 * g)) = make_uint4(lo[0], lo[1], lo[2], lo[3]);
        }
    }

    __syncthreads();   // w1LDS visibility (enc rows are wave-local)

    // keep encode and phase-2 live ranges disjoint: no motion across here
    __builtin_amdgcn_sched_barrier(0);

    // ---------------- W0 fragments: registers, reused by all 4 tiles -------
    v8s w0h[4], w0l[4];
    #pragma unroll
    for (int t = 0; t < 4; ++t) {
        w0h[t] = __builtin_bit_cast(v8s, ws[t * 64 + lane]);
        w0l[t] = __builtin_bit_cast(v8s, ws[256 + t * 64 + lane]);
    }

    // ---------------- Phase 2: 4 M-tiles of 16 points ----------------
    #pragma unroll 1
    for (int t = 0; t < 4; ++t) {
        // launder a zero through opaque asm so LICM cannot hoist the
        // per-tile w1LDS reads / W2 global reads out of this loop (a hoist
        // would add ~76 live regs -> the rounds-5-6 spill disease).
        int tOff = 0;
        asm volatile("" : "+v"(tOff));

        // this tile's enc row for lane's m — also the h0 bounce row.
        uint32_t* hrow = encLDS + (wave * 64 + t * 16 + m) * 36;

        // B-frag of enc: point p = wave*64 + t*16 + m
        const v8s eH = __builtin_bit_cast(v8s, *((const uint4*)(hrow + q * 4)));
        const v8s eL = __builtin_bit_cast(v8s, *((const uint4*)(hrow + 16 + q * 4)));

        // ---- L0: D0[n][p] = W0^T x enc^T, 3-term split ----
        v4f acc0[4];
        #pragma unroll
        for (int nt = 0; nt < 4; ++nt) {
            v4f c = {0.f, 0.f, 0.f, 0.f};
            c = __builtin_amdgcn_mfma_f32_16x16x32_bf16(w0l[nt], eH, c, 0, 0, 0);
            c = __builtin_amdgcn_mfma_f32_16x16x32_bf16(w0h[nt], eL, c, 0, 0, 0);
            c = __builtin_amdgcn_mfma_f32_16x16x32_bf16(w0h[nt], eH, c, 0, 0, 0);
            acc0[nt] = c;
        }

        v4f acc1[4];
        #pragma unroll
        for (int nt = 0; nt < 4; ++nt) acc1[nt] = (v4f){0.f, 0.f, 0.f, 0.f};

        // ---- L1 in two ks-halves, bouncing through this tile's enc rows ----
        // half ks: relu+split acc0[2ks],acc0[2ks+1] (n in [32ks, 32ks+32)) ->
        // bounce -> B-frags (k = 32ks + q*8 + j for point m) -> 12 MFMAs.
        // Safe: eH/eL were read into regs before these writes issue (in-wave
        // DS ordering), and rows belong exclusively to this wave+tile.
        #pragma unroll
        for (int ks = 0; ks < 2; ++ks) {
            #pragma unroll
            for (int nh = 0; nh < 2; ++nh) {
                const int nt = ks * 2 + nh;
                const float r0 = fmaxf(acc0[nt][0], 0.f), r1 = fmaxf(acc0[nt][1], 0.f);
                const float r2 = fmaxf(acc0[nt][2], 0.f), r3 = fmaxf(acc0[nt][3], 0.f);
                uint32_t h0w, l0w, h1w, l1w;
                split2(r0, r1, h0w, l0w);
                split2(r2, r3, h1w, l1w);
                *((uint2*)(hrow + nh * 8 + q * 2))      = make_uint2(h0w, h1w);
                *((uint2*)(hrow + 16 + nh * 8 + q * 2)) = make_uint2(l0w, l1w);
            }
            const v8s bH = __builtin_bit_cast(v8s, *((const uint4*)(hrow + q * 4)));
            const v8s bL = __builtin_bit_cast(v8s, *((const uint4*)(hrow + 16 + q * 4)));

            #pragma unroll
            for (int nt = 0; nt < 4; ++nt) {
                const v8s a_h = __builtin_bit_cast(v8s, w1LDS[tOff + (nt * 2 + ks) * 64 + lane]);
                const v8s a_l = __builtin_bit_cast(v8s, w1LDS[tOff + 512 + (nt * 2 + ks) * 64 + lane]);
                v4f c = acc1[nt];
                c = __builtin_amdgcn_mfma_f32_16x16x32_bf16(a_l, bH, c, 0, 0, 0);
                c = __builtin_amdgcn_mfma_f32_16x16x32_bf16(a_h, bL, c, 0, 0, 0);
                c = __builtin_amdgcn_mfma_f32_16x16x32_bf16(a_h, bH, c, 0, 0, 0);
                acc1[nt] = c;
            }
        }

        // ---- L2 (64->3) in VALU: W2 direct from global (768 B, L1-hot).
        // W2 layout [n][c]: lane needs rows n0..n0+3 = 12 contiguous floats
        // at W2 + n0*3 (48B-aligned). Shuffle to per-channel quads in regs.
        float o0 = 0.f, o1 = 0.f, o2 = 0.f;
        #pragma unroll
        for (int nt = 0; nt < 4; ++nt) {
            const int n0 = nt * 16 + q * 4;
            const float4 g0 = *((const float4*)(W2 + n0 * 3 + tOff));
            const float4 g1 = *((const float4*)(W2 + n0 * 3 + tOff + 4));
            const float4 g2 = *((const float4*)(W2 + n0 * 3 + tOff + 8));
            const float h0r = fmaxf(acc1[nt][0], 0.f), h1r = fmaxf(acc1[nt][1], 0.f);
            const float h2r = fmaxf(acc1[nt][2], 0.f), h3r = fmaxf(acc1[nt][3], 0.f);
            o0 = fmaf(h0r, g0.x, fmaf(h1r, g0.w, fmaf(h2r, g1.z, fmaf(h3r, g2.y, o0))));
            o1 = fmaf(h0r, g0.y, fmaf(h1r, g1.x, fmaf(h2r, g1.w, fmaf(h3r, g2.z, o1))));
            o2 = fmaf(h0r, g0.z, fmaf(h1r, g1.y, fmaf(h2r, g2.x, fmaf(h3r, g2.w, o2))));
        }
        o0 += __shfl_xor(o0, 16); o0 += __shfl_xor(o0, 32);
        o1 += __shfl_xor(o1, 16); o1 += __shfl_xor(o1, 32);
        o2 += __shfl_xor(o2, 16); o2 += __shfl_xor(o2, 32);

        if (lane < 16) {
            const int p = blockBase + wave * 64 + t * 16 + lane;
            out[p] = o0;
            out[NPTS + p] = o1;
            out[2 * NPTS + p] = o2;
        }
    }
}

extern "C" void kernel_launch(void* const* d_in, const int* in_sizes, int n_in,
                              void* d_out, int out_size, void* d_ws, size_t ws_size,
                              hipStream_t stream) {
    const float* xy     = (const float*)d_in[0];
    const float* tables = (const float*)d_in[1];
    const float* W0     = (const float*)d_in[2];
    const float* W1     = (const float*)d_in[3];
    const float* W2     = (const float*)d_in[4];
    float* out = (float*)d_out;
    uint4* ws  = (uint4*)d_ws;   // 1536 x 16B = 24 KB

    hipLaunchKernelGGL(prep_weights, dim3(1), dim3(256), 0, stream, W0, W1, ws);
    hipLaunchKernelGGL(ngp_mfma, dim3(NPTS / 256), dim3(256), 0, stream,
                       xy, tables, W2, ws, out);
}